// Round 8
// baseline (15249.295 us; speedup 1.0000x reference)
//
#include <hip/hip_runtime.h>

// ---------------------------------------------------------------------------
// ResRNN: sequential gated residual RNN, B=64, T=2048, D=32, H=256 (fp32).
//
// R8 = R5 base (best, 13.8ms) + two-tier sc0/sc1 polling.
//  * Ledger R1-R7: dur ~= T * 2 hops; hop pinned ~3.3us across 4 protocol
//    variants -> detection mechanics at system scope are the cost: every
//    sc0+sc1 poll retry is fabric-served, 17 waves x 256 lines queueing.
//  * R8: 3 of 4 poll retries are sc0-ONLY (bypass L1, L2-served: near-zero
//    fabric pressure, ~100x cheaper); every 4th is sc0+sc1 (authoritative,
//    past L2). Producers' sc1 stores write THROUGH their own XCD L2 ->
//    co-XCD consumers (even/odd slice split under round-robin bid->XCD)
//    detect at L2 latency via the cheap legs; cross-XCD parts caught by the
//    sc1 leg. Placement is a PERF heuristic only: per-dword tags + the
//    unconditional sc1 leg give correctness under any placement (stale sc0
//    legs just waste a round). done/back-pressure reads stay sc1.
//  * Everything else byte-identical to R5: 64 RNN wgs (4 rg x 16 slices,
//    weights in 89KB LDS), 2-hop cycle with h1 lookahead, 4 out-wgs,
//    depth-32 ring, fire-and-forget tagged stores.
// ---------------------------------------------------------------------------

#define T_LEN 2048
#define BATCH 64
#define DIM   32
#define HID   256
#define NRG   4
#define RING  32

typedef short    frag_ab __attribute__((ext_vector_type(8)));   // 8 x bf16
typedef float    frag_cd __attribute__((ext_vector_type(4)));   // 4 x f32
typedef float    float4v __attribute__((ext_vector_type(4)));
typedef unsigned uint4v  __attribute__((ext_vector_type(4)));

#define MFMA16(a, b, c) __builtin_amdgcn_mfma_f32_16x16x32_bf16((a), (b), (c), 0, 0, 0)

// LDS slot bases (1 slot = one K-tile of B-frags = 64 lanes * 16 B = 1 KB)
#define S_W1 0
#define S_U1 1
#define S_W2 9
#define S_U2 17
#define S_W3 25
#define S_U3 33
#define S_V3 41
#define S_G1 49   // 49..56 h1-part, 57..64 h2-part
#define S_G2 65   // 65..72 h1, 73..80 h2, 81..88 h3
#define NSLOT 89
#define LDS_BYTES (NSLOT * 64 * 16)   // 91,136 B

// workspace layout
#define H1_OFF   0
#define H1_SZ    (2 * BATCH * HID * 4)              // 128 KB (parity slots)
#define H2R_OFF  (H1_OFF + H1_SZ)
#define H2R_SZ   (RING * BATCH * HID * 4)           // 2 MB
#define H3R_OFF  (H2R_OFF + H2R_SZ)
#define H3R_SZ   (RING * BATCH * HID * 4)           // 2 MB
#define CTL_OFF  (H3R_OFF + H3R_SZ)
#define CTL_SZ   (NRG * 16 * 4)                     // done[rg] pad 16 dw

__device__ __forceinline__ unsigned short f2bf(float f) {
  unsigned u = __builtin_bit_cast(unsigned, f);
  u = (u + 0x7FFFu + ((u >> 16) & 1u)) >> 16;   // RNE
  return (unsigned short)u;
}

__device__ __forceinline__ float fast_tanh(float x) {
  x = fminf(fmaxf(x, -15.f), 15.f);
  float e = __expf(2.f * x);
  return (e - 1.f) / (e + 1.f);
}

__device__ __forceinline__ float fast_sigmoid(float x) {
  x = fminf(fmaxf(x, -30.f), 30.f);
  return 1.f / (1.f + __expf(-x));
}

// ---- memory ops ----
__device__ __forceinline__ void st_sys_u32(unsigned* p, unsigned v) {
  asm volatile("global_store_dword %0, %1, off sc0 sc1" :: "v"(p), "v"(v) : "memory");
}
__device__ __forceinline__ unsigned ld_sys_u32(const unsigned* p) {
  unsigned r;
  asm volatile("global_load_dword %0, %1, off sc0 sc1\n\t"
               "s_waitcnt vmcnt(0)"
               : "=v"(r) : "v"(p) : "memory");
  return r;
}
__device__ __forceinline__ void nap() { asm volatile("s_sleep 1"); }

// 16 x dwordx4 pipelined under one vmcnt -- AUTHORITATIVE (sc0 sc1, past L2)
__device__ __forceinline__ void load16_sys(const unsigned* p, uint4v r[16]) {
  asm volatile(
      "global_load_dwordx4 %0, %16, off sc0 sc1\n\t"
      "global_load_dwordx4 %1, %16, off offset:16 sc0 sc1\n\t"
      "global_load_dwordx4 %2, %16, off offset:128 sc0 sc1\n\t"
      "global_load_dwordx4 %3, %16, off offset:144 sc0 sc1\n\t"
      "global_load_dwordx4 %4, %16, off offset:256 sc0 sc1\n\t"
      "global_load_dwordx4 %5, %16, off offset:272 sc0 sc1\n\t"
      "global_load_dwordx4 %6, %16, off offset:384 sc0 sc1\n\t"
      "global_load_dwordx4 %7, %16, off offset:400 sc0 sc1\n\t"
      "global_load_dwordx4 %8, %16, off offset:512 sc0 sc1\n\t"
      "global_load_dwordx4 %9, %16, off offset:528 sc0 sc1\n\t"
      "global_load_dwordx4 %10, %16, off offset:640 sc0 sc1\n\t"
      "global_load_dwordx4 %11, %16, off offset:656 sc0 sc1\n\t"
      "global_load_dwordx4 %12, %16, off offset:768 sc0 sc1\n\t"
      "global_load_dwordx4 %13, %16, off offset:784 sc0 sc1\n\t"
      "global_load_dwordx4 %14, %16, off offset:896 sc0 sc1\n\t"
      "global_load_dwordx4 %15, %16, off offset:912 sc0 sc1\n\t"
      "s_waitcnt vmcnt(0)"
      : "=v"(r[0]), "=v"(r[1]), "=v"(r[2]), "=v"(r[3]),
        "=v"(r[4]), "=v"(r[5]), "=v"(r[6]), "=v"(r[7]),
        "=v"(r[8]), "=v"(r[9]), "=v"(r[10]), "=v"(r[11]),
        "=v"(r[12]), "=v"(r[13]), "=v"(r[14]), "=v"(r[15])
      : "v"(p)
      : "memory");
}

// CHEAP poll leg (sc0 only: bypass L1, L2-served; fresh for co-XCD producers
// whose sc1 stores wrote through this L2; may be stale for cross-XCD -- the
// sc1 leg above is the unconditional fallback)
__device__ __forceinline__ void load16_l2(const unsigned* p, uint4v r[16]) {
  asm volatile(
      "global_load_dwordx4 %0, %16, off sc0\n\t"
      "global_load_dwordx4 %1, %16, off offset:16 sc0\n\t"
      "global_load_dwordx4 %2, %16, off offset:128 sc0\n\t"
      "global_load_dwordx4 %3, %16, off offset:144 sc0\n\t"
      "global_load_dwordx4 %4, %16, off offset:256 sc0\n\t"
      "global_load_dwordx4 %5, %16, off offset:272 sc0\n\t"
      "global_load_dwordx4 %6, %16, off offset:384 sc0\n\t"
      "global_load_dwordx4 %7, %16, off offset:400 sc0\n\t"
      "global_load_dwordx4 %8, %16, off offset:512 sc0\n\t"
      "global_load_dwordx4 %9, %16, off offset:528 sc0\n\t"
      "global_load_dwordx4 %10, %16, off offset:640 sc0\n\t"
      "global_load_dwordx4 %11, %16, off offset:656 sc0\n\t"
      "global_load_dwordx4 %12, %16, off offset:768 sc0\n\t"
      "global_load_dwordx4 %13, %16, off offset:784 sc0\n\t"
      "global_load_dwordx4 %14, %16, off offset:896 sc0\n\t"
      "global_load_dwordx4 %15, %16, off offset:912 sc0\n\t"
      "s_waitcnt vmcnt(0)"
      : "=v"(r[0]), "=v"(r[1]), "=v"(r[2]), "=v"(r[3]),
        "=v"(r[4]), "=v"(r[5]), "=v"(r[6]), "=v"(r[7]),
        "=v"(r[8]), "=v"(r[9]), "=v"(r[10]), "=v"(r[11]),
        "=v"(r[12]), "=v"(r[13]), "=v"(r[14]), "=v"(r[15])
      : "v"(p)
      : "memory");
}

__device__ __forceinline__ bool unpack_check(const uint4v r[16], unsigned tag16, frag_ab* a) {
  bool ok = true;
  #pragma unroll
  for (int kt = 0; kt < 8; ++kt) {
    #pragma unroll
    for (int j = 0; j < 8; ++j) {
      unsigned w = r[kt * 2 + (j >> 2)][j & 3];
      ok &= ((w >> 16) == tag16);
      a[kt][j] = (short)w;
    }
  }
  return ok;
}

// two-tier poll: rounds 0,1,2 cheap (sc0/L2), round 3 authoritative (sc1);
// repeat. Success on any round with a fully-tagged image.
__device__ __forceinline__ void read_state(const unsigned* p, unsigned tag16, frag_ab* a) {
  unsigned i = 0;
  for (;;) {
    uint4v r[16];
    if ((i & 3u) == 3u) load16_sys(p, r); else load16_l2(p, r);
    if (__all(unpack_check(r, tag16, a))) return;
    ++i;
  }
}

// h1 variant: data is published a full phase earlier -> first try is
// authoritative (usually succeeds immediately), then two-tier.
__device__ __forceinline__ void read_state_h1(const unsigned* p, unsigned tag16, frag_ab* a) {
  {
    uint4v r[16];
    load16_sys(p, r);
    if (__all(unpack_check(r, tag16, a))) return;
  }
  unsigned i = 0;
  for (;;) {
    uint4v r[16];
    if ((i & 3u) == 3u) load16_sys(p, r); else load16_l2(p, r);
    if (__all(unpack_check(r, tag16, a))) return;
    ++i;
  }
}

// publish 4 tagged payload words (rows rr at stride HID), fire-and-forget
__device__ __forceinline__ void publish4(unsigned* pp, unsigned tag16, const float* v) {
  #pragma unroll
  for (int rr = 0; rr < 4; ++rr)
    st_sys_u32(pp + (size_t)rr * HID, (tag16 << 16) | (unsigned)f2bf(v[rr]));
}

__global__ void __launch_bounds__(64, 1)
resrnn_kernel(const float* __restrict__ x,
              const float* __restrict__ W1, const float* __restrict__ U1, const float* __restrict__ b1,
              const float* __restrict__ W2, const float* __restrict__ U2, const float* __restrict__ b2,
              const float* __restrict__ W3, const float* __restrict__ U3, const float* __restrict__ V3,
              const float* __restrict__ b3,
              const float* __restrict__ G1, const float* __restrict__ bg1,
              const float* __restrict__ G2, const float* __restrict__ bg2,
              const float* __restrict__ O1, const float* __restrict__ O2, const float* __restrict__ bo,
              float* __restrict__ out,
              unsigned* __restrict__ h1buf,   // [2][BATCH][HID] tagged
              unsigned* __restrict__ h2r,     // [RING][BATCH][HID] tagged
              unsigned* __restrict__ h3r,     // [RING][BATCH][HID] tagged
              unsigned* __restrict__ done)    // [NRG] pad16, monotonic
{
  extern __shared__ char smem[];
  frag_ab* wf = (frag_ab*)smem;

  const int lane = (int)threadIdx.x;   // block = 1 wave of 64
  const int quad = lane >> 4;
  const int nn   = lane & 15;
  const int bid  = (int)blockIdx.x;

  if (bid < 64) {
    // ------------------------- RNN workgroup -------------------------
    const int rg = bid & 3;
    const int sl = bid >> 2;
    const int colbase = sl * 16;

    // ---- stage weights into LDS as bf16 B-fragments ----
    {
      const float* mats[9] = { W1, U1, W2, U2, W3, U3, V3, G1, G2 };
      const int    nkt[9]  = { 1, 8, 8, 8, 8, 8, 8, 16, 24 };
      int slot = 0;
      for (int m = 0; m < 9; ++m) {
        const float* W = mats[m];
        for (int kt = 0; kt < nkt[m]; ++kt) {
          frag_ab f;
          #pragma unroll
          for (int j = 0; j < 8; ++j) {
            int k = kt * 32 + quad * 8 + j;
            f[j] = (short)f2bf(W[(size_t)k * HID + colbase + nn]);
          }
          wf[slot * 64 + lane] = f;
          ++slot;
        }
      }
    }

    const float b1l  = b1[colbase + nn];
    const float b2l  = b2[colbase + nn];
    const float b3l  = b3[colbase + nn];
    const float bg1l = bg1[colbase + nn];
    const float bg2l = bg2[colbase + nn];

    const frag_ab zf = {0,0,0,0,0,0,0,0};
    frag_ab a1n[8], a3old[8];
    #pragma unroll
    for (int i = 0; i < 8; ++i) { a1n[i] = zf; a3old[i] = zf; }
    float h2l[4] = {0.f,0.f,0.f,0.f};
    float h3l[4] = {0.f,0.f,0.f,0.f};
    float z1l[4] = {1.f,1.f,1.f,1.f};
    float z2l[4] = {1.f,1.f,1.f,1.f};

    const float*    xrow  = x + (size_t)(rg * 16 + nn) * T_LEN * DIM + quad * 8;
    unsigned*       h1pub = h1buf + ((size_t)(rg * 16 + quad * 4)) * HID + colbase + nn;
    const unsigned* h1rd  = h1buf + ((size_t)(rg * 16 + nn)) * HID + quad * 8;
    const size_t    h1st  = (size_t)BATCH * HID;   // parity-slot stride (dwords)

    // ---- prologue: h1(0) = tanh(x(0)@W1 + b1), publish slot0 tag1 ----
    {
      frag_cd p = {0.f,0.f,0.f,0.f};
      float4v xa = *(const float4v*)xrow;
      float4v xb = *(const float4v*)(xrow + 4);
      frag_ab xf;
      #pragma unroll
      for (int j = 0; j < 4; ++j) { xf[j] = (short)f2bf(xa[j]); xf[4 + j] = (short)f2bf(xb[j]); }
      p = MFMA16(xf, wf[S_W1 * 64 + lane], p);
      float v[4];
      #pragma unroll
      for (int rr = 0; rr < 4; ++rr) v[rr] = fast_tanh(p[rr] + b1l);
      publish4(h1pub, 1u, v);
    }
    read_state_h1(h1rd, 1u, a1n);       // a1n = h1(0)

    // p2acc = W2@h1(0) + U2@h2(-1=0)
    frag_cd p2a = {0.f,0.f,0.f,0.f}, p2b = {0.f,0.f,0.f,0.f};
    #pragma unroll
    for (int kt = 0; kt < 4; ++kt) p2a = MFMA16(a1n[kt], wf[(S_W2 + kt) * 64 + lane], p2a);
    #pragma unroll
    for (int kt = 4; kt < 8; ++kt) p2b = MFMA16(a1n[kt], wf[(S_W2 + kt) * 64 + lane], p2b);

    for (int t = 0; t < T_LEN; ++t) {
      const unsigned tag  = (unsigned)(t + 1);
      const int      slot = t & (RING - 1);
      const size_t   rowb = ((size_t)slot * BATCH + rg * 16) * HID;   // rg block base

      // amortized ring back-pressure: cover slots for steps t..t+7 (sc1 read)
      if (t >= RING && (t & 7) == 0) {
        const unsigned need = (unsigned)(t - RING + 8);
        while (ld_sys_u32(done + rg * 16) < need) { nap(); }
      }

      // ---- 1. h2(t) update + publish (p2acc ready, z1 from gates(t-1)) ----
      #pragma unroll
      for (int rr = 0; rr < 4; ++rr) {
        float c = fast_tanh(p2a[rr] + p2b[rr] + b2l);
        h2l[rr] = z1l[rr] * c + (1.f - z1l[rr]) * h2l[rr];
      }
      publish4(h2r + rowb + (size_t)(quad * 4) * HID + colbase + nn, tag, h2l);

      // ---- 2. h1 lookahead: h1(t+1) = tanh(x(t+1)@W1 + U1@h1(t) + b1) ----
      if (t + 1 < T_LEN) {
        frag_cd p = {0.f,0.f,0.f,0.f};
        const float* xp = xrow + (size_t)(t + 1) * DIM;
        float4v xa = *(const float4v*)xp;
        float4v xb = *(const float4v*)(xp + 4);
        frag_ab xf;
        #pragma unroll
        for (int j = 0; j < 4; ++j) { xf[j] = (short)f2bf(xa[j]); xf[4 + j] = (short)f2bf(xb[j]); }
        p = MFMA16(xf, wf[S_W1 * 64 + lane], p);
        #pragma unroll
        for (int kt = 0; kt < 8; ++kt) p = MFMA16(a1n[kt], wf[(S_U1 + kt) * 64 + lane], p);
        float v[4];
        #pragma unroll
        for (int rr = 0; rr < 4; ++rr) v[rr] = fast_tanh(p[rr] + b1l);
        publish4(h1pub + ((size_t)((t + 1) & 1)) * h1st, tag + 1u, v);
      }

      // ---- 3. precompute (indep of h2(t), h3(t)) ----
      frag_cd p3u = {0.f,0.f,0.f,0.f}, pg1a = {0.f,0.f,0.f,0.f}, pg2a = {0.f,0.f,0.f,0.f};
      #pragma unroll
      for (int kt = 0; kt < 8; ++kt) p3u = MFMA16(a3old[kt], wf[(S_U3 + kt) * 64 + lane], p3u);
      #pragma unroll
      for (int kt = 0; kt < 8; ++kt) p3u = MFMA16(a1n[kt], wf[(S_V3 + kt) * 64 + lane], p3u);
      #pragma unroll
      for (int kt = 0; kt < 8; ++kt) pg1a = MFMA16(a1n[kt], wf[(S_G1 + kt) * 64 + lane], pg1a);
      #pragma unroll
      for (int kt = 0; kt < 8; ++kt) pg2a = MFMA16(a1n[kt], wf[(S_G2 + kt) * 64 + lane], pg2a);

      // ---- 4. poll h2(t) full (two-tier) ----
      frag_ab a2[8];
      read_state(h2r + rowb + (size_t)nn * HID + quad * 8, tag, a2);

      // ---- 5. h3(t) update + publish ----
      {
        frag_cd p3 = p3u;
        #pragma unroll
        for (int kt = 0; kt < 8; ++kt) p3 = MFMA16(a2[kt], wf[(S_W3 + kt) * 64 + lane], p3);
        #pragma unroll
        for (int rr = 0; rr < 4; ++rr) {
          float c = fast_tanh(p3[rr] + b3l);
          h3l[rr] = z2l[rr] * c + (1.f - z2l[rr]) * h3l[rr];
        }
        publish4(h3r + rowb + (size_t)(quad * 4) * HID + colbase + nn, tag, h3l);
      }

      // ---- 6. precompute next-iter p2acc + gate h2-parts; poll h1(t+1) ----
      frag_cd pg1b = {0.f,0.f,0.f,0.f}, pg2b = {0.f,0.f,0.f,0.f};
      #pragma unroll
      for (int kt = 0; kt < 8; ++kt) pg1b = MFMA16(a2[kt], wf[(S_G1 + 8 + kt) * 64 + lane], pg1b);
      #pragma unroll
      for (int kt = 0; kt < 8; ++kt) pg2b = MFMA16(a2[kt], wf[(S_G2 + 8 + kt) * 64 + lane], pg2b);
      p2a = (frag_cd){0.f,0.f,0.f,0.f};
      p2b = (frag_cd){0.f,0.f,0.f,0.f};
      #pragma unroll
      for (int kt = 0; kt < 4; ++kt) p2a = MFMA16(a2[kt], wf[(S_U2 + kt) * 64 + lane], p2a);
      #pragma unroll
      for (int kt = 4; kt < 8; ++kt) p2b = MFMA16(a2[kt], wf[(S_U2 + kt) * 64 + lane], p2b);
      if (t + 1 < T_LEN) {
        const size_t po = ((size_t)((t + 1) & 1)) * h1st;
        read_state_h1(h1rd + po, tag + 1u, a1n);   // a1n = h1(t+1)
        #pragma unroll
        for (int kt = 0; kt < 4; ++kt) p2a = MFMA16(a1n[kt], wf[(S_W2 + kt) * 64 + lane], p2a);
        #pragma unroll
        for (int kt = 4; kt < 8; ++kt) p2b = MFMA16(a1n[kt], wf[(S_W2 + kt) * 64 + lane], p2b);
      }

      // ---- 7. poll h3(t) full (two-tier) ----
      read_state(h3r + rowb + (size_t)nn * HID + quad * 8, tag, a3old);

      // ---- 8. gates(t) ----
      frag_cd pg2c = {0.f,0.f,0.f,0.f};
      #pragma unroll
      for (int kt = 0; kt < 8; ++kt) pg2c = MFMA16(a3old[kt], wf[(S_G2 + 16 + kt) * 64 + lane], pg2c);
      #pragma unroll
      for (int rr = 0; rr < 4; ++rr) {
        float z1n = fast_sigmoid(pg1a[rr] + pg1b[rr] + bg1l);
        float z2n = fast_sigmoid(pg2a[rr] + pg2b[rr] + pg2c[rr] + bg2l);
        z1l[rr] = z1n * z2n;
        z2l[rr] = z2n;
      }
    }
  } else {
    // --------------------- output-projection workgroup ---------------------
    const int rg = bid - 64;
    {
      const float* mats[2] = { O1, O2 };
      for (int m = 0; m < 2; ++m)
        for (int nt = 0; nt < 2; ++nt)
          for (int kt = 0; kt < 8; ++kt) {
            frag_ab f;
            #pragma unroll
            for (int j = 0; j < 8; ++j) {
              int k = kt * 32 + quad * 8 + j;
              f[j] = (short)f2bf(mats[m][(size_t)k * DIM + nt * 16 + nn]);
            }
            wf[(m * 16 + nt * 8 + kt) * 64 + lane] = f;
          }
    }
    const float bo0 = bo[nn];
    const float bo1 = bo[16 + nn];

    for (int t = 0; t < T_LEN; ++t) {
      const unsigned tag  = (unsigned)(t + 1);
      const int      slot = t & (RING - 1);
      const size_t   rowb = ((size_t)slot * BATCH + rg * 16) * HID;

      frag_ab a2[8], a3[8];
      read_state(h2r + rowb + (size_t)nn * HID + quad * 8, tag, a2);
      read_state(h3r + rowb + (size_t)nn * HID + quad * 8, tag, a3);

      frag_cd o0 = {0.f,0.f,0.f,0.f}, o1 = {0.f,0.f,0.f,0.f};
      #pragma unroll
      for (int kt = 0; kt < 8; ++kt) {
        o0 = MFMA16(a2[kt], wf[(0 * 16 + 0 * 8 + kt) * 64 + lane], o0);
        o1 = MFMA16(a2[kt], wf[(0 * 16 + 1 * 8 + kt) * 64 + lane], o1);
        o0 = MFMA16(a3[kt], wf[(1 * 16 + 0 * 8 + kt) * 64 + lane], o0);
        o1 = MFMA16(a3[kt], wf[(1 * 16 + 1 * 8 + kt) * 64 + lane], o1);
      }
      #pragma unroll
      for (int rr = 0; rr < 4; ++rr) {
        float* op = out + ((size_t)(rg * 16 + quad * 4 + rr) * T_LEN + t) * DIM;
        op[nn]      = o0[rr] + bo0;
        op[16 + nn] = o1[rr] + bo1;
      }
      // ring data consumed into registers -> free slot
      if (lane == 0) st_sys_u32(done + rg * 16, tag);
    }
  }
}

extern "C" void kernel_launch(void* const* d_in, const int* in_sizes, int n_in,
                              void* d_out, int out_size, void* d_ws, size_t ws_size,
                              hipStream_t stream)
{
  (void)in_sizes; (void)n_in; (void)out_size; (void)ws_size;

  const float* x   = (const float*)d_in[0];
  const float* W1  = (const float*)d_in[1];
  const float* U1  = (const float*)d_in[2];
  const float* b1  = (const float*)d_in[3];
  const float* W2  = (const float*)d_in[4];
  const float* U2  = (const float*)d_in[5];
  const float* b2  = (const float*)d_in[6];
  const float* W3  = (const float*)d_in[7];
  const float* U3  = (const float*)d_in[8];
  const float* V3  = (const float*)d_in[9];
  const float* b3  = (const float*)d_in[10];
  const float* G1  = (const float*)d_in[11];
  const float* bg1 = (const float*)d_in[12];
  const float* G2  = (const float*)d_in[13];
  const float* bg2 = (const float*)d_in[14];
  const float* O1  = (const float*)d_in[15];
  const float* O2  = (const float*)d_in[16];
  const float* bo  = (const float*)d_in[17];

  char* ws = (char*)d_ws;
  unsigned* h1buf = (unsigned*)(ws + H1_OFF);
  unsigned* h2r   = (unsigned*)(ws + H2R_OFF);
  unsigned* h3r   = (unsigned*)(ws + H3R_OFF);
  unsigned* done  = (unsigned*)(ws + CTL_OFF);

  // done[] must start at 0 (ws poisoned 0xAA). Tagged payload buffers need
  // no init (poison tag 0xAAAA never matches a real tag <= 2049).
  hipMemsetAsync(done, 0, CTL_SZ, stream);

  (void)hipFuncSetAttribute((const void*)resrnn_kernel,
                            hipFuncAttributeMaxDynamicSharedMemorySize, LDS_BYTES);

  resrnn_kernel<<<dim3(68), dim3(64), LDS_BYTES, stream>>>(
      x, W1, U1, b1, W2, U2, b2, W3, U3, V3, b3,
      G1, bg1, G2, bg2, O1, O2, bo,
      (float*)d_out, h1buf, h2r, h3r, done);
}

// Round 9
// 14133.908 us; speedup vs baseline: 1.0789x; 1.0789x over previous
//
#include <hip/hip_runtime.h>

// ---------------------------------------------------------------------------
// ResRNN: sequential gated residual RNN, B=64, T=2048, D=32, H=256 (fp32).
//
// R9 = R8 protocol (tag-checked two-tier sc0/sc1 polls, placement-INDEPENDENT
//      correctness) + R3 placement (XCC_ID role claiming -> each row-group
//      cluster co-resident on ONE XCD, sharing its L2).
//  * R8 post-mortem: cheap sc0 poll legs never hit fresh L2 because random
//    placement puts producer/consumer on different XCDs -> FETCH stayed
//    ~460MB, hop stayed ~3.3us. Co-XCD placement is the missing half:
//    producers' sc0+sc1 stores write THROUGH the shared L2; consumers' sc0
//    polls detect at L2 latency. The sc1 leg (every 4th round) remains the
//    unconditional liveness/correctness fallback -> no deadlock under ANY
//    placement (R3's hang was its buffer_inv/plain-store protocol, fixed).
//  * Grid=256, 1 wg/CU (91KB LDS) -> every XCD hosts exactly 32 blocks.
//    Block reads HW_REG_XCC_ID (m09), claims rank via per-XCD atomicAdd
//    (m20). XCD g<4 = row-group g: rank 0..15 -> col-slice wg, rank 16 ->
//    out-wg, rank>16 / XCD>=4 -> exit.
//  * Everything else = R5/R8: 2-hop critical cycle with h1 lookahead,
//    fire-and-forget tagged payload stores ((t+1)<<16|bf16), depth-32 ring,
//    weights in 89KB LDS, 4 out-wgs.
// ---------------------------------------------------------------------------

#define T_LEN 2048
#define BATCH 64
#define DIM   32
#define HID   256
#define NRG   4
#define RING  32

typedef short    frag_ab __attribute__((ext_vector_type(8)));   // 8 x bf16
typedef float    frag_cd __attribute__((ext_vector_type(4)));   // 4 x f32
typedef float    float4v __attribute__((ext_vector_type(4)));
typedef unsigned uint4v  __attribute__((ext_vector_type(4)));

#define MFMA16(a, b, c) __builtin_amdgcn_mfma_f32_16x16x32_bf16((a), (b), (c), 0, 0, 0)

// LDS slot bases (1 slot = one K-tile of B-frags = 64 lanes * 16 B = 1 KB)
#define S_W1 0
#define S_U1 1
#define S_W2 9
#define S_U2 17
#define S_W3 25
#define S_U3 33
#define S_V3 41
#define S_G1 49   // 49..56 h1-part, 57..64 h2-part
#define S_G2 65   // 65..72 h1, 73..80 h2, 81..88 h3
#define NSLOT 89
#define LDS_BYTES (NSLOT * 64 * 16)   // 91,136 B

// workspace layout
#define H1_OFF   0
#define H1_SZ    (2 * BATCH * HID * 4)              // 128 KB (parity slots)
#define H2R_OFF  (H1_OFF + H1_SZ)
#define H2R_SZ   (RING * BATCH * HID * 4)           // 2 MB
#define H3R_OFF  (H2R_OFF + H2R_SZ)
#define H3R_SZ   (RING * BATCH * HID * 4)           // 2 MB
#define CTL_OFF  (H3R_OFF + H3R_SZ)
#define CTL_SZ   ((NRG * 16 + 8) * 4)               // done[rg] pad16 + claim[8]

__device__ __forceinline__ unsigned short f2bf(float f) {
  unsigned u = __builtin_bit_cast(unsigned, f);
  u = (u + 0x7FFFu + ((u >> 16) & 1u)) >> 16;   // RNE
  return (unsigned short)u;
}

__device__ __forceinline__ float fast_tanh(float x) {
  x = fminf(fmaxf(x, -15.f), 15.f);
  float e = __expf(2.f * x);
  return (e - 1.f) / (e + 1.f);
}

__device__ __forceinline__ float fast_sigmoid(float x) {
  x = fminf(fmaxf(x, -30.f), 30.f);
  return 1.f / (1.f + __expf(-x));
}

// ---- memory ops ----
__device__ __forceinline__ void st_sys_u32(unsigned* p, unsigned v) {
  asm volatile("global_store_dword %0, %1, off sc0 sc1" :: "v"(p), "v"(v) : "memory");
}
__device__ __forceinline__ unsigned ld_sys_u32(const unsigned* p) {
  unsigned r;
  asm volatile("global_load_dword %0, %1, off sc0 sc1\n\t"
               "s_waitcnt vmcnt(0)"
               : "=v"(r) : "v"(p) : "memory");
  return r;
}
__device__ __forceinline__ void nap() { asm volatile("s_sleep 1"); }

// 16 x dwordx4 pipelined under one vmcnt -- AUTHORITATIVE (sc0 sc1, past L2)
__device__ __forceinline__ void load16_sys(const unsigned* p, uint4v r[16]) {
  asm volatile(
      "global_load_dwordx4 %0, %16, off sc0 sc1\n\t"
      "global_load_dwordx4 %1, %16, off offset:16 sc0 sc1\n\t"
      "global_load_dwordx4 %2, %16, off offset:128 sc0 sc1\n\t"
      "global_load_dwordx4 %3, %16, off offset:144 sc0 sc1\n\t"
      "global_load_dwordx4 %4, %16, off offset:256 sc0 sc1\n\t"
      "global_load_dwordx4 %5, %16, off offset:272 sc0 sc1\n\t"
      "global_load_dwordx4 %6, %16, off offset:384 sc0 sc1\n\t"
      "global_load_dwordx4 %7, %16, off offset:400 sc0 sc1\n\t"
      "global_load_dwordx4 %8, %16, off offset:512 sc0 sc1\n\t"
      "global_load_dwordx4 %9, %16, off offset:528 sc0 sc1\n\t"
      "global_load_dwordx4 %10, %16, off offset:640 sc0 sc1\n\t"
      "global_load_dwordx4 %11, %16, off offset:656 sc0 sc1\n\t"
      "global_load_dwordx4 %12, %16, off offset:768 sc0 sc1\n\t"
      "global_load_dwordx4 %13, %16, off offset:784 sc0 sc1\n\t"
      "global_load_dwordx4 %14, %16, off offset:896 sc0 sc1\n\t"
      "global_load_dwordx4 %15, %16, off offset:912 sc0 sc1\n\t"
      "s_waitcnt vmcnt(0)"
      : "=v"(r[0]), "=v"(r[1]), "=v"(r[2]), "=v"(r[3]),
        "=v"(r[4]), "=v"(r[5]), "=v"(r[6]), "=v"(r[7]),
        "=v"(r[8]), "=v"(r[9]), "=v"(r[10]), "=v"(r[11]),
        "=v"(r[12]), "=v"(r[13]), "=v"(r[14]), "=v"(r[15])
      : "v"(p)
      : "memory");
}

// CHEAP poll leg (sc0 only: L1-bypass, served by the LOCAL XCD L2 -- fresh
// for co-XCD producers whose sc0+sc1 stores wrote through this L2; the sc1
// leg above is the unconditional cross-XCD/liveness fallback)
__device__ __forceinline__ void load16_l2(const unsigned* p, uint4v r[16]) {
  asm volatile(
      "global_load_dwordx4 %0, %16, off sc0\n\t"
      "global_load_dwordx4 %1, %16, off offset:16 sc0\n\t"
      "global_load_dwordx4 %2, %16, off offset:128 sc0\n\t"
      "global_load_dwordx4 %3, %16, off offset:144 sc0\n\t"
      "global_load_dwordx4 %4, %16, off offset:256 sc0\n\t"
      "global_load_dwordx4 %5, %16, off offset:272 sc0\n\t"
      "global_load_dwordx4 %6, %16, off offset:384 sc0\n\t"
      "global_load_dwordx4 %7, %16, off offset:400 sc0\n\t"
      "global_load_dwordx4 %8, %16, off offset:512 sc0\n\t"
      "global_load_dwordx4 %9, %16, off offset:528 sc0\n\t"
      "global_load_dwordx4 %10, %16, off offset:640 sc0\n\t"
      "global_load_dwordx4 %11, %16, off offset:656 sc0\n\t"
      "global_load_dwordx4 %12, %16, off offset:768 sc0\n\t"
      "global_load_dwordx4 %13, %16, off offset:784 sc0\n\t"
      "global_load_dwordx4 %14, %16, off offset:896 sc0\n\t"
      "global_load_dwordx4 %15, %16, off offset:912 sc0\n\t"
      "s_waitcnt vmcnt(0)"
      : "=v"(r[0]), "=v"(r[1]), "=v"(r[2]), "=v"(r[3]),
        "=v"(r[4]), "=v"(r[5]), "=v"(r[6]), "=v"(r[7]),
        "=v"(r[8]), "=v"(r[9]), "=v"(r[10]), "=v"(r[11]),
        "=v"(r[12]), "=v"(r[13]), "=v"(r[14]), "=v"(r[15])
      : "v"(p)
      : "memory");
}

__device__ __forceinline__ bool unpack_check(const uint4v r[16], unsigned tag16, frag_ab* a) {
  bool ok = true;
  #pragma unroll
  for (int kt = 0; kt < 8; ++kt) {
    #pragma unroll
    for (int j = 0; j < 8; ++j) {
      unsigned w = r[kt * 2 + (j >> 2)][j & 3];
      ok &= ((w >> 16) == tag16);
      a[kt][j] = (short)w;
    }
  }
  return ok;
}

// two-tier poll: rounds 0,1,2 cheap (sc0/local-L2), round 3 authoritative
// (sc1, past L2). Succeeds on any fully-tagged image.
__device__ __forceinline__ void read_state(const unsigned* p, unsigned tag16, frag_ab* a) {
  unsigned i = 0;
  for (;;) {
    uint4v r[16];
    if ((i & 3u) == 3u) load16_sys(p, r); else load16_l2(p, r);
    if (__all(unpack_check(r, tag16, a))) return;
    ++i;
  }
}

// h1 variant: published a full phase earlier -> cheap local-L2 try first.
__device__ __forceinline__ void read_state_h1(const unsigned* p, unsigned tag16, frag_ab* a) {
  unsigned i = 0;
  for (;;) {
    uint4v r[16];
    if ((i & 3u) == 3u) load16_sys(p, r); else load16_l2(p, r);
    if (__all(unpack_check(r, tag16, a))) return;
    ++i;
  }
}

// publish 4 tagged payload words (rows rr at stride HID), fire-and-forget
__device__ __forceinline__ void publish4(unsigned* pp, unsigned tag16, const float* v) {
  #pragma unroll
  for (int rr = 0; rr < 4; ++rr)
    st_sys_u32(pp + (size_t)rr * HID, (tag16 << 16) | (unsigned)f2bf(v[rr]));
}

__global__ void __launch_bounds__(64, 1)
resrnn_kernel(const float* __restrict__ x,
              const float* __restrict__ W1, const float* __restrict__ U1, const float* __restrict__ b1,
              const float* __restrict__ W2, const float* __restrict__ U2, const float* __restrict__ b2,
              const float* __restrict__ W3, const float* __restrict__ U3, const float* __restrict__ V3,
              const float* __restrict__ b3,
              const float* __restrict__ G1, const float* __restrict__ bg1,
              const float* __restrict__ G2, const float* __restrict__ bg2,
              const float* __restrict__ O1, const float* __restrict__ O2, const float* __restrict__ bo,
              float* __restrict__ out,
              unsigned* __restrict__ h1buf,   // [2][BATCH][HID] tagged
              unsigned* __restrict__ h2r,     // [RING][BATCH][HID] tagged
              unsigned* __restrict__ h3r,     // [RING][BATCH][HID] tagged
              unsigned* __restrict__ done,    // [NRG] pad16, monotonic
              unsigned* __restrict__ claim)   // [8] per-XCD rank counters
{
  extern __shared__ char smem[];
  frag_ab* wf = (frag_ab*)smem;

  const int lane = (int)threadIdx.x;   // block = 1 wave of 64
  const int quad = lane >> 4;
  const int nn   = lane & 15;

  // ---- discover physical XCD, claim a role (perf heuristic only:
  //      correctness/liveness hold under ANY resulting placement) ----
  unsigned xcc;
  asm volatile("s_getreg_b32 %0, hwreg(HW_REG_XCC_ID)" : "=s"(xcc));
  xcc &= 7u;
  unsigned rank = 0;
  if (lane == 0) rank = atomicAdd(&claim[xcc], 1u);   // device-scope, non-blocking
  rank = (unsigned)__shfl((int)rank, 0);
  if (xcc >= NRG || rank > 16) return;                // idle block
  const int rg = (int)xcc;

  if (rank < 16) {
    // ------------------------- RNN workgroup -------------------------
    const int sl = (int)rank;
    const int colbase = sl * 16;

    // ---- stage weights into LDS as bf16 B-fragments ----
    {
      const float* mats[9] = { W1, U1, W2, U2, W3, U3, V3, G1, G2 };
      const int    nkt[9]  = { 1, 8, 8, 8, 8, 8, 8, 16, 24 };
      int slot = 0;
      for (int m = 0; m < 9; ++m) {
        const float* W = mats[m];
        for (int kt = 0; kt < nkt[m]; ++kt) {
          frag_ab f;
          #pragma unroll
          for (int j = 0; j < 8; ++j) {
            int k = kt * 32 + quad * 8 + j;
            f[j] = (short)f2bf(W[(size_t)k * HID + colbase + nn]);
          }
          wf[slot * 64 + lane] = f;
          ++slot;
        }
      }
    }

    const float b1l  = b1[colbase + nn];
    const float b2l  = b2[colbase + nn];
    const float b3l  = b3[colbase + nn];
    const float bg1l = bg1[colbase + nn];
    const float bg2l = bg2[colbase + nn];

    const frag_ab zf = {0,0,0,0,0,0,0,0};
    frag_ab a1n[8], a3old[8];
    #pragma unroll
    for (int i = 0; i < 8; ++i) { a1n[i] = zf; a3old[i] = zf; }
    float h2l[4] = {0.f,0.f,0.f,0.f};
    float h3l[4] = {0.f,0.f,0.f,0.f};
    float z1l[4] = {1.f,1.f,1.f,1.f};
    float z2l[4] = {1.f,1.f,1.f,1.f};

    const float*    xrow  = x + (size_t)(rg * 16 + nn) * T_LEN * DIM + quad * 8;
    unsigned*       h1pub = h1buf + ((size_t)(rg * 16 + quad * 4)) * HID + colbase + nn;
    const unsigned* h1rd  = h1buf + ((size_t)(rg * 16 + nn)) * HID + quad * 8;
    const size_t    h1st  = (size_t)BATCH * HID;   // parity-slot stride (dwords)

    // ---- prologue: h1(0) = tanh(x(0)@W1 + b1), publish slot0 tag1 ----
    {
      frag_cd p = {0.f,0.f,0.f,0.f};
      float4v xa = *(const float4v*)xrow;
      float4v xb = *(const float4v*)(xrow + 4);
      frag_ab xf;
      #pragma unroll
      for (int j = 0; j < 4; ++j) { xf[j] = (short)f2bf(xa[j]); xf[4 + j] = (short)f2bf(xb[j]); }
      p = MFMA16(xf, wf[S_W1 * 64 + lane], p);
      float v[4];
      #pragma unroll
      for (int rr = 0; rr < 4; ++rr) v[rr] = fast_tanh(p[rr] + b1l);
      publish4(h1pub, 1u, v);
    }
    read_state_h1(h1rd, 1u, a1n);       // a1n = h1(0)

    // p2acc = W2@h1(0) + U2@h2(-1=0)
    frag_cd p2a = {0.f,0.f,0.f,0.f}, p2b = {0.f,0.f,0.f,0.f};
    #pragma unroll
    for (int kt = 0; kt < 4; ++kt) p2a = MFMA16(a1n[kt], wf[(S_W2 + kt) * 64 + lane], p2a);
    #pragma unroll
    for (int kt = 4; kt < 8; ++kt) p2b = MFMA16(a1n[kt], wf[(S_W2 + kt) * 64 + lane], p2b);

    for (int t = 0; t < T_LEN; ++t) {
      const unsigned tag  = (unsigned)(t + 1);
      const int      slot = t & (RING - 1);
      const size_t   rowb = ((size_t)slot * BATCH + rg * 16) * HID;   // rg block base

      // amortized ring back-pressure: cover slots for steps t..t+7 (sc1 read)
      if (t >= RING && (t & 7) == 0) {
        const unsigned need = (unsigned)(t - RING + 8);
        while (ld_sys_u32(done + rg * 16) < need) { nap(); }
      }

      // ---- 1. h2(t) update + publish (p2acc ready, z1 from gates(t-1)) ----
      #pragma unroll
      for (int rr = 0; rr < 4; ++rr) {
        float c = fast_tanh(p2a[rr] + p2b[rr] + b2l);
        h2l[rr] = z1l[rr] * c + (1.f - z1l[rr]) * h2l[rr];
      }
      publish4(h2r + rowb + (size_t)(quad * 4) * HID + colbase + nn, tag, h2l);

      // ---- 2. h1 lookahead: h1(t+1) = tanh(x(t+1)@W1 + U1@h1(t) + b1) ----
      if (t + 1 < T_LEN) {
        frag_cd p = {0.f,0.f,0.f,0.f};
        const float* xp = xrow + (size_t)(t + 1) * DIM;
        float4v xa = *(const float4v*)xp;
        float4v xb = *(const float4v*)(xp + 4);
        frag_ab xf;
        #pragma unroll
        for (int j = 0; j < 4; ++j) { xf[j] = (short)f2bf(xa[j]); xf[4 + j] = (short)f2bf(xb[j]); }
        p = MFMA16(xf, wf[S_W1 * 64 + lane], p);
        #pragma unroll
        for (int kt = 0; kt < 8; ++kt) p = MFMA16(a1n[kt], wf[(S_U1 + kt) * 64 + lane], p);
        float v[4];
        #pragma unroll
        for (int rr = 0; rr < 4; ++rr) v[rr] = fast_tanh(p[rr] + b1l);
        publish4(h1pub + ((size_t)((t + 1) & 1)) * h1st, tag + 1u, v);
      }

      // ---- 3. precompute (indep of h2(t), h3(t)) ----
      frag_cd p3u = {0.f,0.f,0.f,0.f}, pg1a = {0.f,0.f,0.f,0.f}, pg2a = {0.f,0.f,0.f,0.f};
      #pragma unroll
      for (int kt = 0; kt < 8; ++kt) p3u = MFMA16(a3old[kt], wf[(S_U3 + kt) * 64 + lane], p3u);
      #pragma unroll
      for (int kt = 0; kt < 8; ++kt) p3u = MFMA16(a1n[kt], wf[(S_V3 + kt) * 64 + lane], p3u);
      #pragma unroll
      for (int kt = 0; kt < 8; ++kt) pg1a = MFMA16(a1n[kt], wf[(S_G1 + kt) * 64 + lane], pg1a);
      #pragma unroll
      for (int kt = 0; kt < 8; ++kt) pg2a = MFMA16(a1n[kt], wf[(S_G2 + kt) * 64 + lane], pg2a);

      // ---- 4. poll h2(t) full (two-tier, co-XCD L2 fast path) ----
      frag_ab a2[8];
      read_state(h2r + rowb + (size_t)nn * HID + quad * 8, tag, a2);

      // ---- 5. h3(t) update + publish ----
      {
        frag_cd p3 = p3u;
        #pragma unroll
        for (int kt = 0; kt < 8; ++kt) p3 = MFMA16(a2[kt], wf[(S_W3 + kt) * 64 + lane], p3);
        #pragma unroll
        for (int rr = 0; rr < 4; ++rr) {
          float c = fast_tanh(p3[rr] + b3l);
          h3l[rr] = z2l[rr] * c + (1.f - z2l[rr]) * h3l[rr];
        }
        publish4(h3r + rowb + (size_t)(quad * 4) * HID + colbase + nn, tag, h3l);
      }

      // ---- 6. precompute next-iter p2acc + gate h2-parts; poll h1(t+1) ----
      frag_cd pg1b = {0.f,0.f,0.f,0.f}, pg2b = {0.f,0.f,0.f,0.f};
      #pragma unroll
      for (int kt = 0; kt < 8; ++kt) pg1b = MFMA16(a2[kt], wf[(S_G1 + 8 + kt) * 64 + lane], pg1b);
      #pragma unroll
      for (int kt = 0; kt < 8; ++kt) pg2b = MFMA16(a2[kt], wf[(S_G2 + 8 + kt) * 64 + lane], pg2b);
      p2a = (frag_cd){0.f,0.f,0.f,0.f};
      p2b = (frag_cd){0.f,0.f,0.f,0.f};
      #pragma unroll
      for (int kt = 0; kt < 4; ++kt) p2a = MFMA16(a2[kt], wf[(S_U2 + kt) * 64 + lane], p2a);
      #pragma unroll
      for (int kt = 4; kt < 8; ++kt) p2b = MFMA16(a2[kt], wf[(S_U2 + kt) * 64 + lane], p2b);
      if (t + 1 < T_LEN) {
        const size_t po = ((size_t)((t + 1) & 1)) * h1st;
        read_state_h1(h1rd + po, tag + 1u, a1n);   // a1n = h1(t+1)
        #pragma unroll
        for (int kt = 0; kt < 4; ++kt) p2a = MFMA16(a1n[kt], wf[(S_W2 + kt) * 64 + lane], p2a);
        #pragma unroll
        for (int kt = 4; kt < 8; ++kt) p2b = MFMA16(a1n[kt], wf[(S_W2 + kt) * 64 + lane], p2b);
      }

      // ---- 7. poll h3(t) full (two-tier) ----
      read_state(h3r + rowb + (size_t)nn * HID + quad * 8, tag, a3old);

      // ---- 8. gates(t) ----
      frag_cd pg2c = {0.f,0.f,0.f,0.f};
      #pragma unroll
      for (int kt = 0; kt < 8; ++kt) pg2c = MFMA16(a3old[kt], wf[(S_G2 + 16 + kt) * 64 + lane], pg2c);
      #pragma unroll
      for (int rr = 0; rr < 4; ++rr) {
        float z1n = fast_sigmoid(pg1a[rr] + pg1b[rr] + bg1l);
        float z2n = fast_sigmoid(pg2a[rr] + pg2b[rr] + pg2c[rr] + bg2l);
        z1l[rr] = z1n * z2n;
        z2l[rr] = z2n;
      }
    }
  } else {
    // --------------------- output-projection workgroup ---------------------
    {
      const float* mats[2] = { O1, O2 };
      for (int m = 0; m < 2; ++m)
        for (int nt = 0; nt < 2; ++nt)
          for (int kt = 0; kt < 8; ++kt) {
            frag_ab f;
            #pragma unroll
            for (int j = 0; j < 8; ++j) {
              int k = kt * 32 + quad * 8 + j;
              f[j] = (short)f2bf(mats[m][(size_t)k * DIM + nt * 16 + nn]);
            }
            wf[(m * 16 + nt * 8 + kt) * 64 + lane] = f;
          }
    }
    const float bo0 = bo[nn];
    const float bo1 = bo[16 + nn];

    for (int t = 0; t < T_LEN; ++t) {
      const unsigned tag  = (unsigned)(t + 1);
      const int      slot = t & (RING - 1);
      const size_t   rowb = ((size_t)slot * BATCH + rg * 16) * HID;

      frag_ab a2[8], a3[8];
      read_state(h2r + rowb + (size_t)nn * HID + quad * 8, tag, a2);
      read_state(h3r + rowb + (size_t)nn * HID + quad * 8, tag, a3);

      frag_cd o0 = {0.f,0.f,0.f,0.f}, o1 = {0.f,0.f,0.f,0.f};
      #pragma unroll
      for (int kt = 0; kt < 8; ++kt) {
        o0 = MFMA16(a2[kt], wf[(0 * 16 + 0 * 8 + kt) * 64 + lane], o0);
        o1 = MFMA16(a2[kt], wf[(0 * 16 + 1 * 8 + kt) * 64 + lane], o1);
        o0 = MFMA16(a3[kt], wf[(1 * 16 + 0 * 8 + kt) * 64 + lane], o0);
        o1 = MFMA16(a3[kt], wf[(1 * 16 + 1 * 8 + kt) * 64 + lane], o1);
      }
      #pragma unroll
      for (int rr = 0; rr < 4; ++rr) {
        float* op = out + ((size_t)(rg * 16 + quad * 4 + rr) * T_LEN + t) * DIM;
        op[nn]      = o0[rr] + bo0;
        op[16 + nn] = o1[rr] + bo1;
      }
      // ring data consumed into registers -> free slot
      if (lane == 0) st_sys_u32(done + rg * 16, tag);
    }
  }
}

extern "C" void kernel_launch(void* const* d_in, const int* in_sizes, int n_in,
                              void* d_out, int out_size, void* d_ws, size_t ws_size,
                              hipStream_t stream)
{
  (void)in_sizes; (void)n_in; (void)out_size; (void)ws_size;

  const float* x   = (const float*)d_in[0];
  const float* W1  = (const float*)d_in[1];
  const float* U1  = (const float*)d_in[2];
  const float* b1  = (const float*)d_in[3];
  const float* W2  = (const float*)d_in[4];
  const float* U2  = (const float*)d_in[5];
  const float* b2  = (const float*)d_in[6];
  const float* W3  = (const float*)d_in[7];
  const float* U3  = (const float*)d_in[8];
  const float* V3  = (const float*)d_in[9];
  const float* b3  = (const float*)d_in[10];
  const float* G1  = (const float*)d_in[11];
  const float* bg1 = (const float*)d_in[12];
  const float* G2  = (const float*)d_in[13];
  const float* bg2 = (const float*)d_in[14];
  const float* O1  = (const float*)d_in[15];
  const float* O2  = (const float*)d_in[16];
  const float* bo  = (const float*)d_in[17];

  char* ws = (char*)d_ws;
  unsigned* h1buf = (unsigned*)(ws + H1_OFF);
  unsigned* h2r   = (unsigned*)(ws + H2R_OFF);
  unsigned* h3r   = (unsigned*)(ws + H3R_OFF);
  unsigned* done  = (unsigned*)(ws + CTL_OFF);
  unsigned* claim = done + NRG * 16;

  // done[] + claim[] must start at 0 (ws poisoned 0xAA). Tagged payload
  // buffers need no init (poison tag 0xAAAA never matches a tag <= 2049).
  hipMemsetAsync(done, 0, CTL_SZ, stream);

  (void)hipFuncSetAttribute((const void*)resrnn_kernel,
                            hipFuncAttributeMaxDynamicSharedMemorySize, LDS_BYTES);

  // grid = 256: 1 wg/CU (91KB LDS) -> every XCD hosts exactly 32 claimants.
  resrnn_kernel<<<dim3(256), dim3(64), LDS_BYTES, stream>>>(
      x, W1, U1, b1, W2, U2, b2, W3, U3, V3, b3,
      G1, bg1, G2, bg2, O1, O2, bo,
      (float*)d_out, h1buf, h2r, h3r, done, claim);
}